// Round 10
// baseline (180.486 us; speedup 1.0000x reference)
//
#include <hip/hip_runtime.h>

typedef unsigned short bfu;
typedef __attribute__((ext_vector_type(8))) short short8;
typedef __attribute__((ext_vector_type(4))) float f32x4;

__device__ __forceinline__ float bf2f(bfu u){
  union { unsigned int i; float f; } v; v.i = ((unsigned int)u) << 16; return v.f;
}
__device__ __forceinline__ bfu f2bf(float f){
  union { float f; unsigned int i; } v; v.f = f;
  unsigned int r = (v.i + 0x7FFFu + ((v.i >> 16) & 1u)) >> 16;
  return (bfu)r;
}
__device__ __forceinline__ float fexp2(float x){ return __builtin_amdgcn_exp2f(x); }
__device__ __forceinline__ float flog2(float x){ return __builtin_amdgcn_logf(x); }
__device__ __forceinline__ float softplusf(float x){
  float t = fexp2(-fabsf(x) * 1.44269504088896f);
  return fmaxf(x, 0.f) + 0.69314718055995f * flog2(1.f + t);
}
__device__ __forceinline__ void gload16(const bfu* g, bfu* l){
  __builtin_amdgcn_global_load_lds((const __attribute__((address_space(1))) unsigned int*)g,
                                   (__attribute__((address_space(3))) unsigned int*)l, 16, 0, 0);
}

// ---------------- weights conversion kernel (x conversion now fused into GEMM1) ----------------
__global__ __launch_bounds__(256) void cvt_w_kernel(const float* __restrict__ W_in, const float* __restrict__ W_out,
                                                    const float* __restrict__ W_x,
                                                    bfu* __restrict__ WinT, bfu* __restrict__ WoutT,
                                                    float* __restrict__ WxT){
  int h = blockIdx.x * 256 + threadIdx.x;
  if (h < 786432){
    int r = h % 512, c = h / 512;
    WinT[h] = f2bf(W_in[(size_t)r * 1536 + c]);
  } else if (h < 786432 + 393216){
    int h2 = h - 786432;
    int r = h2 % 768, c = h2 / 768;
    WoutT[h2] = f2bf(W_out[(size_t)r * 512 + c]);
  } else if (h < 786432 + 393216 + 6144){
    int h2 = h - (786432 + 393216);
    int n = h2 / 768, k = h2 % 768;
    WxT[h2] = W_x[(size_t)k * 8 + n];
  }
}

// ---------------- GEMM1: xz = x(f32!) @ WinT^T, fused f32->bf16 A-staging ----------------
// BM=256, BN=128, BK=64, 512 thr (8 waves: 4M x 2N, 64x64/wave).
// A: reg-staged from f32 x (issue-first float4 loads -> f2bf -> swizzled ds_write).
// B: global_load_lds with pre-swizzled source.  2-phase issue-first dbuf loop.
// Epilogue: silu, split to xssm/siluz (bf16).
__global__ __launch_bounds__(512)
void gemm_f1(const float* __restrict__ x, const bfu* __restrict__ Bt,
             bfu* __restrict__ out0, bfu* __restrict__ out1, int NBN)
{
  constexpr int KK = 512;
  constexpr int NT = KK / 64;
  // per buf: A 256x64 (16384 elems, 32KB) + B 128x64 (8192 elems, 16KB)
  __shared__ bfu LDS[2 * 24576];
  const int tid  = threadIdx.x;
  const int lane = tid & 63;
  const int w    = tid >> 6;
  const int wr   = w >> 1, wc = w & 1;

  // T1: XCD-aware bijective swizzle (grid % 8 == 0)
  const int cpx = gridDim.x >> 3;
  const int id  = blockIdx.x;
  const int nid = (id & 7) * cpx + (id >> 3);
  const int bn  = nid % NBN;
  const int bm  = nid / NBN;

  // A reg-staging addressing: thread t -> row (t>>3) within 64-row pass, slot t&7
  const int arow = tid >> 3;                 // 0..63
  const int aslot = tid & 7;                 // 16B bf16 slot (8 elems = 8 f32)
  const float* gx = x + ((size_t)(bm * 256 + arow)) * 512 + aslot * 8;
  // swizzled LDS write slot (T2: slot ^ (row&7); row&7 == arow&7 since pass stride 64)
  const int wslot = (aslot ^ (arow & 7)) * 8;

  // B staging (gload_lds, pre-swizzled global source)
  const int srow = tid >> 3;                       // 0..63
  const int scol = ((tid & 7) ^ (srow & 7)) * 8;
  const bfu* gB = Bt + ((size_t)(bn * 128 + srow)) * KK + scol;

  float4 av[4][2];
  auto ALOAD = [&](int t){
    const int k0 = t * 64;
    #pragma unroll
    for (int p = 0; p < 4; p++){
      const float* src = gx + (size_t)(p * 64) * 512 + k0;
      av[p][0] = *(const float4*)src;
      av[p][1] = *(const float4*)(src + 4);
    }
  };
  auto ACVT = [&](int buf){
    bfu* dst = (bfu*)LDS + buf * 24576;
    #pragma unroll
    for (int p = 0; p < 4; p++){
      short8 pk;
      pk[0] = (short)f2bf(av[p][0].x); pk[1] = (short)f2bf(av[p][0].y);
      pk[2] = (short)f2bf(av[p][0].z); pk[3] = (short)f2bf(av[p][0].w);
      pk[4] = (short)f2bf(av[p][1].x); pk[5] = (short)f2bf(av[p][1].y);
      pk[6] = (short)f2bf(av[p][1].z); pk[7] = (short)f2bf(av[p][1].w);
      *(short8*)&dst[(p * 64 + arow) * 64 + wslot] = pk;
    }
  };
  auto STAGE_B = [&](int t, int buf){
    const int k0 = t * 64;
    bfu* dst = (bfu*)LDS + buf * 24576 + 16384 + tid * 8;
    #pragma unroll
    for (int j = 0; j < 2; j++)
      gload16(gB + (size_t)(j * 64) * KK + k0, dst + j * 4096);
  };

  f32x4 acc[4][4];
  #pragma unroll
  for (int i = 0; i < 4; i++)
    #pragma unroll
    for (int j = 0; j < 4; j++)
      #pragma unroll
      for (int r = 0; r < 4; r++) acc[i][j][r] = 0.f;

  // prologue: tile 0 fully staged
  ALOAD(0);
  STAGE_B(0, 0);
  ACVT(0);
  asm volatile("s_waitcnt vmcnt(0) lgkmcnt(0)" ::: "memory");
  __builtin_amdgcn_s_barrier();

  int cur = 0;
  for (int t = 0; t < NT; ++t){
    // 1) issue next tile's loads FIRST
    if (t + 1 < NT){
      ALOAD(t + 1);
      STAGE_B(t + 1, cur ^ 1);
      __builtin_amdgcn_sched_barrier(0);   // pin prefetch issue before compute
    }

    // 2) compute current tile
    const bfu* Ab = (const bfu*)LDS + cur * 24576;
    const bfu* Bb = Ab + 16384;
    #pragma unroll
    for (int kk = 0; kk < 2; kk++){
      short8 a[4], b[4];
      const int sA = ((kk * 4 + (lane >> 4)) ^ (lane & 7)) * 8;
      #pragma unroll
      for (int m = 0; m < 4; m++){
        int r = wr * 64 + m * 16 + (lane & 15);
        a[m] = *(const short8*)&Ab[r * 64 + sA];
      }
      #pragma unroll
      for (int n = 0; n < 4; n++){
        int r = wc * 64 + n * 16 + (lane & 15);
        b[n] = *(const short8*)&Bb[r * 64 + sA];
      }
      #pragma unroll
      for (int m = 0; m < 4; m++)
        #pragma unroll
        for (int n = 0; n < 4; n++)
          acc[m][n] = __builtin_amdgcn_mfma_f32_16x16x32_bf16(a[m], b[n], acc[m][n], 0, 0, 0);
    }

    // 3) write the converted A of tile t+1 (f32 loads have had the compute to land),
    //    drain staging, one barrier, swap
    if (t + 1 < NT){
      ACVT(cur ^ 1);
      asm volatile("s_waitcnt vmcnt(0) lgkmcnt(0)" ::: "memory");
      __builtin_amdgcn_s_barrier();
      cur ^= 1;
    }
  }

  #pragma unroll
  for (int m = 0; m < 4; m++){
    #pragma unroll
    for (int n = 0; n < 4; n++){
      const int row0 = bm * 256 + wr * 64 + m * 16 + (lane >> 4) * 4;
      const int col  = bn * 128 + wc * 64 + n * 16 + (lane & 15);
      #pragma unroll
      for (int r = 0; r < 4; r++){
        float v = acc[m][n][r];
        int row = row0 + r;
        float s = v / (1.f + __expf(-v));   // silu
        if (col < 768) out0[(size_t)row * 768 + col]         = f2bf(s);
        else           out1[(size_t)row * 768 + (col - 768)] = f2bf(s);
      }
    }
  }
}

// ---------------- GEMM2 (bf16 A): 2-phase issue-first dbuf (r9 structure) ----------------
template<int KK>
__global__ __launch_bounds__(512)
void gemm_2p(const bfu* __restrict__ Amat, const bfu* __restrict__ Bt,
             float* __restrict__ out0, int NBN, int N)
{
  constexpr int NT = KK / 64;
  __shared__ bfu LDS[2 * 24576];
  const int tid  = threadIdx.x;
  const int lane = tid & 63;
  const int w    = tid >> 6;
  const int wr   = w >> 1, wc = w & 1;

  const int cpx = gridDim.x >> 3;
  const int id  = blockIdx.x;
  const int nid = (id & 7) * cpx + (id >> 3);
  const int bn  = nid % NBN;
  const int bm  = nid / NBN;

  const int srow = tid >> 3;
  const int scol = ((tid & 7) ^ (srow & 7)) * 8;
  const bfu* gA = Amat + ((size_t)(bm * 256 + srow)) * KK + scol;
  const bfu* gB = Bt   + ((size_t)(bn * 128 + srow)) * KK + scol;

  auto STAGE = [&](int t, int buf){
    const int k0 = t * 64;
    bfu* dst = (bfu*)LDS + buf * 24576 + tid * 8;
    #pragma unroll
    for (int i = 0; i < 4; i++)
      gload16(gA + (size_t)(i * 64) * KK + k0, dst + i * 4096);
    #pragma unroll
    for (int j = 0; j < 2; j++)
      gload16(gB + (size_t)(j * 64) * KK + k0, dst + 16384 + j * 4096);
  };

  f32x4 acc[4][4];
  #pragma unroll
  for (int i = 0; i < 4; i++)
    #pragma unroll
    for (int j = 0; j < 4; j++)
      #pragma unroll
      for (int r = 0; r < 4; r++) acc[i][j][r] = 0.f;

  STAGE(0, 0);
  asm volatile("s_waitcnt vmcnt(0)" ::: "memory");
  __builtin_amdgcn_s_barrier();

  int cur = 0;
  for (int t = 0; t < NT; ++t){
    if (t + 1 < NT) STAGE(t + 1, cur ^ 1);

    const bfu* Ab = (const bfu*)LDS + cur * 24576;
    const bfu* Bb = Ab + 16384;
    #pragma unroll
    for (int kk = 0; kk < 2; kk++){
      short8 a[4], b[4];
      const int sA = ((kk * 4 + (lane >> 4)) ^ (lane & 7)) * 8;
      #pragma unroll
      for (int m = 0; m < 4; m++){
        int r = wr * 64 + m * 16 + (lane & 15);
        a[m] = *(const short8*)&Ab[r * 64 + sA];
      }
      #pragma unroll
      for (int n = 0; n < 4; n++){
        int r = wc * 64 + n * 16 + (lane & 15);
        b[n] = *(const short8*)&Bb[r * 64 + sA];
      }
      #pragma unroll
      for (int m = 0; m < 4; m++)
        #pragma unroll
        for (int n = 0; n < 4; n++)
          acc[m][n] = __builtin_amdgcn_mfma_f32_16x16x32_bf16(a[m], b[n], acc[m][n], 0, 0, 0);
    }

    if (t + 1 < NT){
      asm volatile("s_waitcnt vmcnt(0)" ::: "memory");
      __builtin_amdgcn_s_barrier();
      cur ^= 1;
    }
  }

  #pragma unroll
  for (int m = 0; m < 4; m++){
    #pragma unroll
    for (int n = 0; n < 4; n++){
      const int row0 = bm * 256 + wr * 64 + m * 16 + (lane >> 4) * 4;
      const int col  = bn * 128 + wc * 64 + n * 16 + (lane & 15);
      #pragma unroll
      for (int r = 0; r < 4; r++)
        out0[(size_t)(row0 + r) * N + col] = acc[m][n][r];
    }
  }
}

// ---------------- u = xssm @ W_x  (uses WxT [8][768], coalesced) ----------------
__global__ __launch_bounds__(256) void u_kernel(const bfu* __restrict__ xssm, const float* __restrict__ WxT,
                                                float* __restrict__ u){
  int wid = threadIdx.x >> 6, lane = threadIdx.x & 63;
  int row = blockIdx.x * 4 + wid;
  const bfu* xr = xssm + (size_t)row * 768;
  float acc[8];
  #pragma unroll
  for (int n = 0; n < 8; n++) acc[n] = 0.f;
  #pragma unroll
  for (int i = 0; i < 3; i++){
    int kb = i * 256 + lane * 4;
    ushort4 xq = *(const ushort4*)(xr + kb);
    float x0 = bf2f(xq.x), x1 = bf2f(xq.y), x2 = bf2f(xq.z), x3 = bf2f(xq.w);
    #pragma unroll
    for (int n = 0; n < 8; n++){
      float4 wv = *(const float4*)(WxT + (size_t)n * 768 + kb);
      acc[n] += x0 * wv.x + x1 * wv.y + x2 * wv.z + x3 * wv.w;
    }
  }
  #pragma unroll
  for (int n = 0; n < 8; n++){
    #pragma unroll
    for (int off = 32; off >= 1; off >>= 1) acc[n] += __shfl_xor(acc[n], off, 64);
  }
  if (lane == 0){
    float4 o0 = { acc[0], acc[1], acc[2], acc[3] };
    float4 o1 = { acc[4], acc[5], acc[6], acc[7] };
    *(float4*)(u + (size_t)row * 8)     = o0;
    *(float4*)(u + (size_t)row * 8 + 4) = o1;
  }
}

// ---------------- scan phase 1: per-chunk local scan, delta inline ----------------
__global__ __launch_bounds__(128) void scan_phase1(const bfu* __restrict__ xssm, const float* __restrict__ u,
    const float* __restrict__ Wdt, const float* __restrict__ bdt, const float* __restrict__ A_log,
    float* __restrict__ Pws, float* __restrict__ Hws){
  int tid = threadIdx.x;
  int bid = blockIdx.x;
  int b = bid / 192; int rem = bid % 192;
  int c = rem / 3;   int dblk = rem % 3;
  int d0 = dblk * 256 + tid * 2;
  float Al2[2][8], H[2][8], Wr[2][8], bd[2], S[2];
  #pragma unroll
  for (int j = 0; j < 2; j++){
    bd[j] = bdt[d0 + j];
    S[j] = 0.f;
    #pragma unroll
    for (int n = 0; n < 8; n++){
      Al2[j][n] = -__expf(A_log[(size_t)(d0 + j) * 8 + n]) * 1.4426950408889634f;
      Wr[j][n]  = Wdt[(size_t)n * 768 + d0 + j];
      H[j][n] = 0.f;
    }
  }
  int r0 = b * 2048 + c * 32;
  size_t base = (size_t)r0 * 768 + d0;
  #pragma unroll 8
  for (int i = 0; i < 32; i++){
    float4 u0 = *(const float4*)(u + (size_t)(r0 + i) * 8);
    float4 u1 = *(const float4*)(u + (size_t)(r0 + i) * 8 + 4);
    ushort2 xq = *(const ushort2*)(xssm + base + (size_t)i * 768);
    #pragma unroll
    for (int j = 0; j < 2; j++){
      float xt = bf2f(j == 0 ? xq.x : xq.y);
      float dv = bd[j] + u0.x * Wr[j][0] + u0.y * Wr[j][1] + u0.z * Wr[j][2] + u0.w * Wr[j][3]
                       + u1.x * Wr[j][4] + u1.y * Wr[j][5] + u1.z * Wr[j][6] + u1.w * Wr[j][7];
      float dt = softplusf(dv);
      float dx = dt * xt;
      S[j] += dt;
      #pragma unroll
      for (int n = 0; n < 8; n++){
        float e = fexp2(dt * Al2[j][n]);
        H[j][n] = e * H[j][n] + dx;
      }
    }
  }
  size_t o = (((size_t)b * 64 + c) * 768 + d0) * 8;
  #pragma unroll
  for (int j = 0; j < 2; j++){
    float4 p0, p1;
    p0.x = fexp2(S[j] * Al2[j][0]); p0.y = fexp2(S[j] * Al2[j][1]);
    p0.z = fexp2(S[j] * Al2[j][2]); p0.w = fexp2(S[j] * Al2[j][3]);
    p1.x = fexp2(S[j] * Al2[j][4]); p1.y = fexp2(S[j] * Al2[j][5]);
    p1.z = fexp2(S[j] * Al2[j][6]); p1.w = fexp2(S[j] * Al2[j][7]);
    float4 h0 = { H[j][0], H[j][1], H[j][2], H[j][3] };
    float4 h1 = { H[j][4], H[j][5], H[j][6], H[j][7] };
    *(float4*)(Pws + o + j * 8)     = p0;
    *(float4*)(Pws + o + j * 8 + 4) = p1;
    *(float4*)(Hws + o + j * 8)     = h0;
    *(float4*)(Hws + o + j * 8 + 4) = h1;
  }
}

// ---------------- scan phase 2: combine chunks; Hin written IN-PLACE into Pws ----------------
__global__ __launch_bounds__(256) void scan_phase2(float* __restrict__ Pws, const float* __restrict__ Hws){
  int g = blockIdx.x * 256 + threadIdx.x;   // 49152 = 8*768*8
  int within = g % 6144;                    // d*8+n
  int b = g / 6144;
  size_t base = (size_t)b * 64 * 6144 + within;
  float hin = 0.f;
  #pragma unroll 8
  for (int c = 0; c < 64; c++){
    size_t idx = base + (size_t)c * 6144;
    float p = Pws[idx], hh = Hws[idx];
    Pws[idx] = hin;                         // h_in for chunk c
    hin = p * hin + hh;
  }
}

// ---------------- scan phase 3: re-run chunk with h_in, delta inline, fuse gate ----------------
__global__ __launch_bounds__(128) void scan_phase3(const bfu* __restrict__ xssm, const float* __restrict__ u,
    const float* __restrict__ Wdt, const float* __restrict__ bdt, const float* __restrict__ A_log,
    const float* __restrict__ Dp, const bfu* __restrict__ siluz, const float* __restrict__ Hin,
    bfu* __restrict__ yz){
  int tid = threadIdx.x;
  int bid = blockIdx.x;
  int b = bid / 192; int rem = bid % 192;
  int c = rem / 3;   int dblk = rem % 3;
  int d0 = dblk * 256 + tid * 2;
  float Al2[2][8], H[2][8], Wr[2][8], bd[2], Dd[2];
  size_t o = (((size_t)b * 64 + c) * 768 + d0) * 8;
  #pragma unroll
  for (int j = 0; j < 2; j++){
    bd[j] = bdt[d0 + j];
    Dd[j] = Dp[d0 + j];
    float4 h0 = *(const float4*)(Hin + o + j * 8);
    float4 h1 = *(const float4*)(Hin + o + j * 8 + 4);
    H[j][0] = h0.x; H[j][1] = h0.y; H[j][2] = h0.z; H[j][3] = h0.w;
    H[j][4] = h1.x; H[j][5] = h1.y; H[j][6] = h1.z; H[j][7] = h1.w;
    #pragma unroll
    for (int n = 0; n < 8; n++){
      Al2[j][n] = -__expf(A_log[(size_t)(d0 + j) * 8 + n]) * 1.4426950408889634f;
      Wr[j][n]  = Wdt[(size_t)n * 768 + d0 + j];
    }
  }
  int r0 = b * 2048 + c * 32;
  size_t base = (size_t)r0 * 768 + d0;
  #pragma unroll 8
  for (int i = 0; i < 32; i++){
    float4 u0 = *(const float4*)(u + (size_t)(r0 + i) * 8);
    float4 u1 = *(const float4*)(u + (size_t)(r0 + i) * 8 + 4);
    ushort2 xq = *(const ushort2*)(xssm + base + (size_t)i * 768);
    ushort2 zq = *(const ushort2*)(siluz + base + (size_t)i * 768);
    ushort2 oq;
    #pragma unroll
    for (int j = 0; j < 2; j++){
      float xt = bf2f(j == 0 ? xq.x : xq.y);
      float dv = bd[j] + u0.x * Wr[j][0] + u0.y * Wr[j][1] + u0.z * Wr[j][2] + u0.w * Wr[j][3]
                       + u1.x * Wr[j][4] + u1.y * Wr[j][5] + u1.z * Wr[j][6] + u1.w * Wr[j][7];
      float dt = softplusf(dv);
      float dx = dt * xt;
      float y = Dd[j] * xt;
      #pragma unroll
      for (int n = 0; n < 8; n++){
        float e = fexp2(dt * Al2[j][n]);
        H[j][n] = e * H[j][n] + dx;
        y += H[j][n];
      }
      float sz = bf2f(j == 0 ? zq.x : zq.y);
      bfu r = f2bf(y * sz);
      if (j == 0) oq.x = r; else oq.y = r;
    }
    *(ushort2*)(yz + base + (size_t)i * 768) = oq;
  }
}

extern "C" void kernel_launch(void* const* d_in, const int* in_sizes, int n_in,
                              void* d_out, int out_size, void* d_ws, size_t ws_size,
                              hipStream_t stream){
  const float* x     = (const float*)d_in[0];
  const float* W_in  = (const float*)d_in[1];
  const float* A_log = (const float*)d_in[2];
  const float* D_par = (const float*)d_in[3];
  const float* W_x   = (const float*)d_in[4];
  const float* W_dt  = (const float*)d_in[5];
  const float* b_dt  = (const float*)d_in[6];
  const float* W_out = (const float*)d_in[7];
  float* out = (float*)d_out;
  (void)in_sizes; (void)n_in; (void)out_size; (void)ws_size;

  char* base = (char*)d_ws;
  size_t off = 0;
  auto alloc = [&](size_t bytes)->char*{
    char* p = base + off; off += (bytes + 255) & ~(size_t)255; return p;
  };
  bfu*   WinT  = (bfu*)  alloc((size_t)1536 * 512 * 2);
  bfu*   WoutT = (bfu*)  alloc((size_t)512 * 768 * 2);
  float* WxT   = (float*)alloc((size_t)8 * 768 * 4);
  bfu*   xssm  = (bfu*)  alloc((size_t)16384 * 768 * 2);
  bfu*   siluz = (bfu*)  alloc((size_t)16384 * 768 * 2);
  float* u     = (float*)alloc((size_t)16384 * 8 * 4);
  float* Pws   = (float*)alloc((size_t)8 * 64 * 768 * 8 * 4);
  float* Hws   = (float*)alloc((size_t)8 * 64 * 768 * 8 * 4);
  bfu*   yz    = (bfu*)  alloc((size_t)16384 * 768 * 2);

  // 1) weight conversions only (x conversion fused into GEMM1)
  cvt_w_kernel<<<4632, 256, 0, stream>>>(W_in, W_out, W_x, WinT, WoutT, WxT);
  // 2) GEMM1: xz = x @ W_in (f32 A fused-converted), silu+split epilogue
  gemm_f1<<<768, 512, 0, stream>>>(x, WinT, xssm, siluz, 12);
  // 3) u = xssm @ W_x
  u_kernel<<<4096, 256, 0, stream>>>(xssm, WxT, u);
  // 4-6) chunked scan
  scan_phase1<<<1536, 128, 0, stream>>>(xssm, u, W_dt, b_dt, A_log, Pws, Hws);
  scan_phase2<<<192, 256, 0, stream>>>(Pws, Hws);
  scan_phase3<<<1536, 128, 0, stream>>>(xssm, u, W_dt, b_dt, A_log, D_par, siluz, Pws, yz);
  // 7) GEMM2: out = yz @ W_out (f32 out)
  gemm_2p<768><<<256, 512, 0, stream>>>(yz, WoutT, out, 4, 512);
}

// Round 11
// 163.216 us; speedup vs baseline: 1.1058x; 1.1058x over previous
//
#include <hip/hip_runtime.h>

typedef unsigned short bfu;
typedef __attribute__((ext_vector_type(8))) short short8;
typedef __attribute__((ext_vector_type(4))) float f32x4;

__device__ __forceinline__ float bf2f(bfu u){
  union { unsigned int i; float f; } v; v.i = ((unsigned int)u) << 16; return v.f;
}
__device__ __forceinline__ bfu f2bf(float f){
  union { float f; unsigned int i; } v; v.f = f;
  unsigned int r = (v.i + 0x7FFFu + ((v.i >> 16) & 1u)) >> 16;
  return (bfu)r;
}
__device__ __forceinline__ float fexp2(float x){ return __builtin_amdgcn_exp2f(x); }
__device__ __forceinline__ float flog2(float x){ return __builtin_amdgcn_logf(x); }
__device__ __forceinline__ float softplusf(float x){
  float t = fexp2(-fabsf(x) * 1.44269504088896f);
  return fmaxf(x, 0.f) + 0.69314718055995f * flog2(1.f + t);
}
__device__ __forceinline__ void gload16(const bfu* g, bfu* l){
  __builtin_amdgcn_global_load_lds((const __attribute__((address_space(1))) unsigned int*)g,
                                   (__attribute__((address_space(3))) unsigned int*)l, 16, 0, 0);
}

// ---------------- fused conversion kernel ----------------
__global__ __launch_bounds__(256) void cvt_all_kernel(const float* __restrict__ x, bfu* __restrict__ x_bf,
                                                      const float* __restrict__ W_in, const float* __restrict__ W_out,
                                                      const float* __restrict__ W_x,
                                                      bfu* __restrict__ WinT, bfu* __restrict__ WoutT,
                                                      float* __restrict__ WxT){
  int g = blockIdx.x * 256 + threadIdx.x;
  if (g < 2097152){
    float4 v = ((const float4*)x)[g];
    ushort4 o;
    o.x = f2bf(v.x); o.y = f2bf(v.y); o.z = f2bf(v.z); o.w = f2bf(v.w);
    ((ushort4*)x_bf)[g] = o;
    return;
  }
  int h = g - 2097152;
  if (h < 786432){
    int r = h % 512, c = h / 512;
    WinT[h] = f2bf(W_in[(size_t)r * 1536 + c]);
  } else if (h < 786432 + 393216){
    int h2 = h - 786432;
    int r = h2 % 768, c = h2 / 768;
    WoutT[h2] = f2bf(W_out[(size_t)r * 512 + c]);
  } else if (h < 786432 + 393216 + 6144){
    int h2 = h - (786432 + 393216);
    int n = h2 / 768, k = h2 % 768;
    WxT[h2] = W_x[(size_t)k * 8 + n];
  }
}

// ---------------- MFMA GEMM: C = A(MxK) * Bt(NxK)^T  (r5-proven structure) ----------------
// BM x 128 tile, BK=64, THREADS = BM*2 (BM=256 -> 8 waves, BM=128 -> 4 waves),
// per-wave 64x64 output.  Single-buffered LDS, 2 __syncthreads per K-tile.
// T1 XCD swizzle; T2 LDS swizzle via pre-swizzled global source + swizzled read.
// Small BM=128 variant gives 32KB LDS -> multiple blocks/CU for short-grid GEMM2.
template<int EPI, int BM, int KK>
__global__ __launch_bounds__(BM * 2)
void gemm_sb(const bfu* __restrict__ Amat, const bfu* __restrict__ Bt,
             void* __restrict__ out0, void* __restrict__ out1,
             int NBN, int N)
{
  constexpr int BN = 128;
  constexpr int THREADS = BM * 2;
  constexpr int RPI = THREADS / 8;       // rows covered per staging issue
  __shared__ bfu As[BM * 64];
  __shared__ bfu Bs[BN * 64];
  const int tid  = threadIdx.x;
  const int lane = tid & 63;
  const int w    = tid >> 6;
  const int wr   = w >> 1, wc = w & 1;   // (BM/64 x 2) wave grid, 64x64 each

  // T1: XCD-aware bijective swizzle (grid % 8 == 0)
  const int cpx = gridDim.x >> 3;
  const int id  = blockIdx.x;
  const int nid = (id & 7) * cpx + (id >> 3);
  const int bn  = nid % NBN;
  const int bm  = nid / NBN;

  // staging: issue covers RPI rows; thread t -> row (t>>3), 16B slot (t&7)
  const int srow = tid >> 3;
  const int scol = ((tid & 7) ^ (srow & 7)) * 8;   // pre-swizzled global col (T2)
  const bfu* gA = Amat + ((size_t)(bm * BM + srow)) * KK + scol;
  const bfu* gB = Bt   + ((size_t)(bn * BN + srow)) * KK + scol;
  bfu* lA = As + srow * 64 + (tid & 7) * 8;
  bfu* lB = Bs + srow * 64 + (tid & 7) * 8;

  f32x4 acc[4][4];
  #pragma unroll
  for (int i = 0; i < 4; i++)
    #pragma unroll
    for (int j = 0; j < 4; j++)
      #pragma unroll
      for (int r = 0; r < 4; r++) acc[i][j][r] = 0.f;

  for (int k0 = 0; k0 < KK; k0 += 64){
    #pragma unroll
    for (int i = 0; i < BM / RPI; i++)
      gload16(gA + (size_t)(i * RPI) * KK + k0, lA + i * RPI * 64);
    #pragma unroll
    for (int j = 0; j < BN / RPI; j++)
      gload16(gB + (size_t)(j * RPI) * KK + k0, lB + j * RPI * 64);
    __syncthreads();

    #pragma unroll
    for (int kk = 0; kk < 2; kk++){
      short8 a[4], b[4];
      const int sA = ((kk * 4 + (lane >> 4)) ^ (lane & 7)) * 8;
      #pragma unroll
      for (int m = 0; m < 4; m++){
        int r = wr * 64 + m * 16 + (lane & 15);
        a[m] = *(const short8*)&As[r * 64 + sA];
      }
      #pragma unroll
      for (int n = 0; n < 4; n++){
        int r = wc * 64 + n * 16 + (lane & 15);
        b[n] = *(const short8*)&Bs[r * 64 + sA];
      }
      #pragma unroll
      for (int m = 0; m < 4; m++)
        #pragma unroll
        for (int n = 0; n < 4; n++)
          acc[m][n] = __builtin_amdgcn_mfma_f32_16x16x32_bf16(a[m], b[n], acc[m][n], 0, 0, 0);
    }
    __syncthreads();
  }

  #pragma unroll
  for (int m = 0; m < 4; m++){
    #pragma unroll
    for (int n = 0; n < 4; n++){
      const int row0 = bm * BM + wr * 64 + m * 16 + (lane >> 4) * 4;
      const int col  = bn * BN + wc * 64 + n * 16 + (lane & 15);
      #pragma unroll
      for (int r = 0; r < 4; r++){
        float v = acc[m][n][r];
        int row = row0 + r;
        if (EPI == 0){
          float s = v / (1.f + __expf(-v));   // silu
          if (col < 768) ((bfu*)out0)[(size_t)row * 768 + col]         = f2bf(s);
          else           ((bfu*)out1)[(size_t)row * 768 + (col - 768)] = f2bf(s);
        } else {
          ((float*)out0)[(size_t)row * N + col] = v;
        }
      }
    }
  }
}

// ---------------- u = xssm @ W_x  (uses WxT [8][768], coalesced) ----------------
__global__ __launch_bounds__(256) void u_kernel(const bfu* __restrict__ xssm, const float* __restrict__ WxT,
                                                float* __restrict__ u){
  int wid = threadIdx.x >> 6, lane = threadIdx.x & 63;
  int row = blockIdx.x * 4 + wid;
  const bfu* xr = xssm + (size_t)row * 768;
  float acc[8];
  #pragma unroll
  for (int n = 0; n < 8; n++) acc[n] = 0.f;
  #pragma unroll
  for (int i = 0; i < 3; i++){
    int kb = i * 256 + lane * 4;
    ushort4 xq = *(const ushort4*)(xr + kb);
    float x0 = bf2f(xq.x), x1 = bf2f(xq.y), x2 = bf2f(xq.z), x3 = bf2f(xq.w);
    #pragma unroll
    for (int n = 0; n < 8; n++){
      float4 wv = *(const float4*)(WxT + (size_t)n * 768 + kb);
      acc[n] += x0 * wv.x + x1 * wv.y + x2 * wv.z + x3 * wv.w;
    }
  }
  #pragma unroll
  for (int n = 0; n < 8; n++){
    #pragma unroll
    for (int off = 32; off >= 1; off >>= 1) acc[n] += __shfl_xor(acc[n], off, 64);
  }
  if (lane == 0){
    float4 o0 = { acc[0], acc[1], acc[2], acc[3] };
    float4 o1 = { acc[4], acc[5], acc[6], acc[7] };
    *(float4*)(u + (size_t)row * 8)     = o0;
    *(float4*)(u + (size_t)row * 8 + 4) = o1;
  }
}

// ---------------- scan phase 1: per-chunk local scan, delta inline ----------------
__global__ __launch_bounds__(128) void scan_phase1(const bfu* __restrict__ xssm, const float* __restrict__ u,
    const float* __restrict__ Wdt, const float* __restrict__ bdt, const float* __restrict__ A_log,
    float* __restrict__ Pws, float* __restrict__ Hws){
  int tid = threadIdx.x;
  int bid = blockIdx.x;
  int b = bid / 192; int rem = bid % 192;
  int c = rem / 3;   int dblk = rem % 3;
  int d0 = dblk * 256 + tid * 2;
  float Al2[2][8], H[2][8], Wr[2][8], bd[2], S[2];
  #pragma unroll
  for (int j = 0; j < 2; j++){
    bd[j] = bdt[d0 + j];
    S[j] = 0.f;
    #pragma unroll
    for (int n = 0; n < 8; n++){
      Al2[j][n] = -__expf(A_log[(size_t)(d0 + j) * 8 + n]) * 1.4426950408889634f;
      Wr[j][n]  = Wdt[(size_t)n * 768 + d0 + j];
      H[j][n] = 0.f;
    }
  }
  int r0 = b * 2048 + c * 32;
  size_t base = (size_t)r0 * 768 + d0;
  #pragma unroll 8
  for (int i = 0; i < 32; i++){
    float4 u0 = *(const float4*)(u + (size_t)(r0 + i) * 8);
    float4 u1 = *(const float4*)(u + (size_t)(r0 + i) * 8 + 4);
    ushort2 xq = *(const ushort2*)(xssm + base + (size_t)i * 768);
    #pragma unroll
    for (int j = 0; j < 2; j++){
      float xt = bf2f(j == 0 ? xq.x : xq.y);
      float dv = bd[j] + u0.x * Wr[j][0] + u0.y * Wr[j][1] + u0.z * Wr[j][2] + u0.w * Wr[j][3]
                       + u1.x * Wr[j][4] + u1.y * Wr[j][5] + u1.z * Wr[j][6] + u1.w * Wr[j][7];
      float dt = softplusf(dv);
      float dx = dt * xt;
      S[j] += dt;
      #pragma unroll
      for (int n = 0; n < 8; n++){
        float e = fexp2(dt * Al2[j][n]);
        H[j][n] = e * H[j][n] + dx;
      }
    }
  }
  size_t o = (((size_t)b * 64 + c) * 768 + d0) * 8;
  #pragma unroll
  for (int j = 0; j < 2; j++){
    float4 p0, p1;
    p0.x = fexp2(S[j] * Al2[j][0]); p0.y = fexp2(S[j] * Al2[j][1]);
    p0.z = fexp2(S[j] * Al2[j][2]); p0.w = fexp2(S[j] * Al2[j][3]);
    p1.x = fexp2(S[j] * Al2[j][4]); p1.y = fexp2(S[j] * Al2[j][5]);
    p1.z = fexp2(S[j] * Al2[j][6]); p1.w = fexp2(S[j] * Al2[j][7]);
    float4 h0 = { H[j][0], H[j][1], H[j][2], H[j][3] };
    float4 h1 = { H[j][4], H[j][5], H[j][6], H[j][7] };
    *(float4*)(Pws + o + j * 8)     = p0;
    *(float4*)(Pws + o + j * 8 + 4) = p1;
    *(float4*)(Hws + o + j * 8)     = h0;
    *(float4*)(Hws + o + j * 8 + 4) = h1;
  }
}

// ---------------- scan phase 2: combine chunks; Hin written IN-PLACE into Pws ----------------
__global__ __launch_bounds__(256) void scan_phase2(float* __restrict__ Pws, const float* __restrict__ Hws){
  int g = blockIdx.x * 256 + threadIdx.x;   // 49152 = 8*768*8
  int within = g % 6144;                    // d*8+n
  int b = g / 6144;
  size_t base = (size_t)b * 64 * 6144 + within;
  float hin = 0.f;
  #pragma unroll 8
  for (int c = 0; c < 64; c++){
    size_t idx = base + (size_t)c * 6144;
    float p = Pws[idx], hh = Hws[idx];
    Pws[idx] = hin;                         // h_in for chunk c
    hin = p * hin + hh;
  }
}

// ---------------- scan phase 3: re-run chunk with h_in, delta inline, fuse gate ----------------
__global__ __launch_bounds__(128) void scan_phase3(const bfu* __restrict__ xssm, const float* __restrict__ u,
    const float* __restrict__ Wdt, const float* __restrict__ bdt, const float* __restrict__ A_log,
    const float* __restrict__ Dp, const bfu* __restrict__ siluz, const float* __restrict__ Hin,
    bfu* __restrict__ yz){
  int tid = threadIdx.x;
  int bid = blockIdx.x;
  int b = bid / 192; int rem = bid % 192;
  int c = rem / 3;   int dblk = rem % 3;
  int d0 = dblk * 256 + tid * 2;
  float Al2[2][8], H[2][8], Wr[2][8], bd[2], Dd[2];
  size_t o = (((size_t)b * 64 + c) * 768 + d0) * 8;
  #pragma unroll
  for (int j = 0; j < 2; j++){
    bd[j] = bdt[d0 + j];
    Dd[j] = Dp[d0 + j];
    float4 h0 = *(const float4*)(Hin + o + j * 8);
    float4 h1 = *(const float4*)(Hin + o + j * 8 + 4);
    H[j][0] = h0.x; H[j][1] = h0.y; H[j][2] = h0.z; H[j][3] = h0.w;
    H[j][4] = h1.x; H[j][5] = h1.y; H[j][6] = h1.z; H[j][7] = h1.w;
    #pragma unroll
    for (int n = 0; n < 8; n++){
      Al2[j][n] = -__expf(A_log[(size_t)(d0 + j) * 8 + n]) * 1.4426950408889634f;
      Wr[j][n]  = Wdt[(size_t)n * 768 + d0 + j];
    }
  }
  int r0 = b * 2048 + c * 32;
  size_t base = (size_t)r0 * 768 + d0;
  #pragma unroll 8
  for (int i = 0; i < 32; i++){
    float4 u0 = *(const float4*)(u + (size_t)(r0 + i) * 8);
    float4 u1 = *(const float4*)(u + (size_t)(r0 + i) * 8 + 4);
    ushort2 xq = *(const ushort2*)(xssm + base + (size_t)i * 768);
    ushort2 zq = *(const ushort2*)(siluz + base + (size_t)i * 768);
    ushort2 oq;
    #pragma unroll
    for (int j = 0; j < 2; j++){
      float xt = bf2f(j == 0 ? xq.x : xq.y);
      float dv = bd[j] + u0.x * Wr[j][0] + u0.y * Wr[j][1] + u0.z * Wr[j][2] + u0.w * Wr[j][3]
                       + u1.x * Wr[j][4] + u1.y * Wr[j][5] + u1.z * Wr[j][6] + u1.w * Wr[j][7];
      float dt = softplusf(dv);
      float dx = dt * xt;
      float y = Dd[j] * xt;
      #pragma unroll
      for (int n = 0; n < 8; n++){
        float e = fexp2(dt * Al2[j][n]);
        H[j][n] = e * H[j][n] + dx;
        y += H[j][n];
      }
      float sz = bf2f(j == 0 ? zq.x : zq.y);
      bfu r = f2bf(y * sz);
      if (j == 0) oq.x = r; else oq.y = r;
    }
    *(ushort2*)(yz + base + (size_t)i * 768) = oq;
  }
}

extern "C" void kernel_launch(void* const* d_in, const int* in_sizes, int n_in,
                              void* d_out, int out_size, void* d_ws, size_t ws_size,
                              hipStream_t stream){
  const float* x     = (const float*)d_in[0];
  const float* W_in  = (const float*)d_in[1];
  const float* A_log = (const float*)d_in[2];
  const float* D_par = (const float*)d_in[3];
  const float* W_x   = (const float*)d_in[4];
  const float* W_dt  = (const float*)d_in[5];
  const float* b_dt  = (const float*)d_in[6];
  const float* W_out = (const float*)d_in[7];
  float* out = (float*)d_out;
  (void)in_sizes; (void)n_in; (void)out_size; (void)ws_size;

  char* base = (char*)d_ws;
  size_t off = 0;
  auto alloc = [&](size_t bytes)->char*{
    char* p = base + off; off += (bytes + 255) & ~(size_t)255; return p;
  };
  bfu*   x_bf  = (bfu*)  alloc((size_t)16384 * 512 * 2);
  bfu*   WinT  = (bfu*)  alloc((size_t)1536 * 512 * 2);
  bfu*   WoutT = (bfu*)  alloc((size_t)512 * 768 * 2);
  float* WxT   = (float*)alloc((size_t)8 * 768 * 4);
  bfu*   xssm  = (bfu*)  alloc((size_t)16384 * 768 * 2);
  bfu*   siluz = (bfu*)  alloc((size_t)16384 * 768 * 2);
  float* u     = (float*)alloc((size_t)16384 * 8 * 4);
  float* Pws   = (float*)alloc((size_t)8 * 64 * 768 * 8 * 4);
  float* Hws   = (float*)alloc((size_t)8 * 64 * 768 * 8 * 4);
  bfu*   yz    = (bfu*)  alloc((size_t)16384 * 768 * 2);

  // 1) fused conversions: x->bf16 + weight transposes
  cvt_all_kernel<<<12824, 256, 0, stream>>>(x, x_bf, W_in, W_out, W_x, WinT, WoutT, WxT);
  // 2) GEMM1 (r5-proven): BM=256, grid = (16384/256)*(1536/128) = 64*12 = 768
  gemm_sb<0, 256, 512><<<768, 512, 0, stream>>>(x_bf, WinT, xssm, siluz, 12, 1536);
  // 3) u = xssm @ W_x
  u_kernel<<<4096, 256, 0, stream>>>(xssm, WxT, u);
  // 4-6) chunked scan
  scan_phase1<<<1536, 128, 0, stream>>>(xssm, u, W_dt, b_dt, A_log, Pws, Hws);
  scan_phase2<<<192, 256, 0, stream>>>(Pws, Hws);
  scan_phase3<<<1536, 128, 0, stream>>>(xssm, u, W_dt, b_dt, A_log, D_par, siluz, Pws, yz);
  // 7) GEMM2: BM=128 (32KB LDS, many blocks/CU), grid = (16384/128)*(512/128) = 128*4 = 512
  gemm_sb<1, 128, 768><<<512, 256, 0, stream>>>(yz, WoutT, out, nullptr, 4, 512);
}